// Round 7
// baseline (592.850 us; speedup 1.0000x reference)
//
#include <hip/hip_runtime.h>

typedef __attribute__((ext_vector_type(8))) short bf16x8;
typedef __attribute__((ext_vector_type(4))) float f32x4;
typedef __attribute__((ext_vector_type(4))) unsigned short us4;

typedef __attribute__((address_space(3))) void lds_void_t;
typedef const __attribute__((address_space(1))) void gbl_void_t;

__device__ __forceinline__ unsigned short f2bf(float f) {
    union { float f; unsigned int i; } x; x.f = f;
    unsigned int u = x.i;
    unsigned int r = (u + 0x7FFFu + ((u >> 16) & 1u)) >> 16;  // RNE
    return (unsigned short)r;
}

// ---------------------------------------------------------------------------
// f32 -> bf16 convert, 4 elems/thread, grid-stride.
// ---------------------------------------------------------------------------
__global__ __launch_bounds__(256) void conv_f32_bf16(
    const float* __restrict__ src, unsigned short* __restrict__ dst, long n4)
{
    long i = (long)blockIdx.x * blockDim.x + threadIdx.x;
    const long stride = (long)gridDim.x * blockDim.x;
    const float4* s = (const float4*)src;
    for (; i < n4; i += stride) {
        float4 v = s[i];
        us4 o = { f2bf(v.x), f2bf(v.y), f2bf(v.z), f2bf(v.w) };
        *(us4*)&dst[i * 4] = o;
    }
}

// ---------------------------------------------------------------------------
// Transpose: W(K x N) f32 -> Wt(N x K) bf16. 64x64 LDS tiles.
// ---------------------------------------------------------------------------
__global__ __launch_bounds__(256) void transpose_f32_bf16(
    const float* __restrict__ W, unsigned short* __restrict__ Wt, int K, int N)
{
    __shared__ unsigned short t[64][65];
    const int n0 = blockIdx.x * 64, k0 = blockIdx.y * 64;
    const int tid = threadIdx.x;
#pragma unroll
    for (int i = 0; i < 16; i++) {
        const int idx = tid + i * 256;
        const int r = idx >> 6, c = idx & 63;
        t[c][r] = f2bf(W[(long)(k0 + r) * N + (n0 + c)]);
    }
    __syncthreads();
#pragma unroll
    for (int i = 0; i < 16; i++) {
        const int idx = tid + i * 256;
        const int r = idx >> 6, c = idx & 63;
        Wt[(long)(n0 + r) * K + (k0 + c)] = t[r][c];
    }
}

// ---------------------------------------------------------------------------
// Mask summary: mf[b][row][nblk] = any(mask[b][row][nblk*256 .. +256)).
// ---------------------------------------------------------------------------
__global__ __launch_bounds__(256) void mask_any256(
    const unsigned char* __restrict__ mask, unsigned char* __restrict__ mf)
{
    const long row = blockIdx.x;                 // b*1024 + s
    const int tid = threadIdx.x;
    const unsigned int v = *(const unsigned int*)&mask[(row << 10) + (tid << 2)];
    const unsigned long long b = __ballot(v != 0u);
    if ((tid & 63) == 0) mf[(row << 2) + (tid >> 6)] = b ? 1 : 0;
}

// ---------------------------------------------------------------------------
// 256x256 bf16 GEMM, 8 waves (512 thr), wave tile 128x64, acc 8x4 f32x4,
// BK=32, TWO LDS buffers (64 KiB) -> 2 blocks/CU. launch_bounds (512,2)
// (r5 lesson: (512,4) caps VGPR at 64 -> total spill).
// r7 change (single variable vs r6): ONE barrier per K-tile, no forced
// lgkmcnt(0), no sched_barrier fences around the compute. r6 forced a full
// 12-deep ds_read drain + fence before the first MFMA every tile -> ~300+cyc
// read latency strictly serial with ~600cyc MFMA (matches 23% MfmaUtil across
// 3 schedule families). The compiler's own counted lgkmcnt insertion
// interleaves reads with MFMA (m97 asm evidence); let it.
//   per tile t: VMW(0) [drains stage(t), issued 1 tile ago]; SB; s_barrier;
//   SB; {ds_read 12 || stage t+1 || 32 MFMA — compiler-scheduled}.
// Correctness:
//  RAW (DMA->read): every wave VMW(0)+barrier before any read of tile t. SB
//    fences stop read hoisting above the barrier.
//  WAR (read->DMA overwrite): wave Y's reads of buf^1 at t-1 are operands of
//    its MFMAs -> drained (in-order DS returns) before Y's last MFMA of t-1,
//    hence before Y reaches top-bar(t), hence before any stage(t+1) issues.
// T2 swizzle pair (verified, 0 bank conflicts): stage source col chunk =
// (lane&3)^((lane>>3)&3), LDS dest linear; read chunk = quad^((l16>>1)&3).
// SM: 0 bf16 row-major (swapped mfma -> regs = 4 consecutive cols, us4)
//     1 VhT head-split-transpose (UNswapped, us4 along s)
//     2 f32 row-major (swapped, float4)
//     3 scores-fused: P=exp(s*it), mask via per-(row,nblk) flag; us4 stores;
//        row-sums -> Lp[(nb*4+wn)][z][row] (16 exclusive slots)
//     4 PV: scale by 1/sum_16(Lp), Ls[256] LDS table from prologue
// SWZ: 0 none | 1 within-plane XCD chunk | 2 whole-grid z-chunked XCD swizzle
// ---------------------------------------------------------------------------
#define VMW(n) asm volatile("s_waitcnt vmcnt(" #n ")" ::: "memory")

template <int SM, int SWZ>
__global__ __launch_bounds__(512, 2) void gemm8w_bt(
    const unsigned short* __restrict__ A,
    const unsigned short* __restrict__ Bt,
    void* __restrict__ C,
    int K, int lda, int ldb, int ldc,
    long Ah, long Ab, long Bh, long Bb, long Ch, long Cb,
    int bg,
    const unsigned char* __restrict__ mask,
    const unsigned char* __restrict__ mflag,
    float* __restrict__ L,
    float inv_temp, int b0)
{
    const int tid  = threadIdx.x;
    const int wave = tid >> 6;
    const int lane = tid & 63;
    const int quad = lane >> 4;
    const int l16  = lane & 15;
    const int wm   = wave >> 2;   // 0..1 : M-wave (rows wm*128..+127)
    const int wn   = wave & 3;    // 0..3 : N-wave (cols wn*64..+63)

    int z, m0, n0;
    if (SWZ == 2) {
        const int gx = gridDim.x, gxy = gx * gridDim.y;
        const int tot = gxy * gridDim.z;
        int Lb = (blockIdx.z * gridDim.y + blockIdx.y) * gx + blockIdx.x;
        int t = (Lb & 7) * (tot >> 3) + (Lb >> 3);
        z = t / gxy;
        const int rem = t - z * gxy;
        const int by = rem / gx;
        m0 = by << 8; n0 = (rem - by * gx) << 8;
    } else if (SWZ == 1) {
        z = blockIdx.z;
        int lin = blockIdx.y * gridDim.x + blockIdx.x;
        const int q8 = (gridDim.x * gridDim.y) >> 3;
        lin = (lin & 7) * q8 + (lin >> 3);
        const int by = lin / gridDim.x;
        m0 = by << 8; n0 = (lin - by * gridDim.x) << 8;
    } else {
        z = blockIdx.z; m0 = blockIdx.y << 8; n0 = blockIdx.x << 8;
    }

    const int h  = z / bg;
    const int bi = z - h * bg;
    A  += h * Ah + (long)bi * Ab;
    Bt += h * Bh + (long)bi * Bb;

    __shared__ __align__(16) unsigned short As[2][8192];  // [buf][256 rows x 32 k]
    __shared__ __align__(16) unsigned short Bs[2][8192];
    __shared__ float Ls[256];  // PV: summed softmax denominators

    // ---- staging: linear LDS dest, inverse-swizzled global source ----
    const int srow = lane >> 2;
    const int scol = ((lane & 3) ^ ((lane >> 3) & 3)) << 3;
    const unsigned short* Ag = A + (long)(m0 + wave * 16 + srow) * lda + scol;
    const unsigned short* Bg = Bt + (long)(n0 + wave * 16 + srow) * ldb + scol;

#define STA(buf, hh, kt) __builtin_amdgcn_global_load_lds( \
        (gbl_void_t*)(Ag + (long)(hh) * 128 * lda + (kt)), \
        (lds_void_t*)&As[buf][((hh) << 12) + (wave << 9)], 16, 0, 0)
#define STB(buf, hh, kt) __builtin_amdgcn_global_load_lds( \
        (gbl_void_t*)(Bg + (long)(hh) * 128 * ldb + (kt)), \
        (lds_void_t*)&Bs[buf][((hh) << 12) + (wave << 9)], 16, 0, 0)

    // prologue: stage tile 0 FIRST (max distance to the t=0 VMW(0))
    STA(0, 0, 0); STA(0, 1, 0); STB(0, 0, 0); STB(0, 1, 0);

    if (SM == 4) {
        if (tid < 256) {
            const float* Lz = L + ((long)z << 10) + m0 + tid;
            const long sls = (long)gridDim.z << 10;
            float s = 0.f;
#pragma unroll
            for (int sl = 0; sl < 16; sl++) s += Lz[sl * sls];
            Ls[tid] = s;
        }
    }

    // ---- fragment reads (swizzled addr, verified pair with staging) ----
    const int kof = (quad ^ ((l16 >> 1) & 3)) << 3;
    const int raA = ((wm * 128 + l16) << 5) + kof;
    const int raB = ((wn * 64 + l16) << 5) + kof;

    bf16x8 ar[8];
    bf16x8 br[4];
    f32x4 acc[8][4];
#pragma unroll
    for (int i2 = 0; i2 < 8; i2++)
#pragma unroll
        for (int j2 = 0; j2 < 4; j2++) acc[i2][j2] = (f32x4){0.f, 0.f, 0.f, 0.f};

#define LDA8(buf) do { _Pragma("unroll") for (int u = 0; u < 8; u++) \
    ar[u] = *(const bf16x8*)&As[buf][raA + u * 512]; } while (0)
#define LDB4(buf) do { _Pragma("unroll") for (int v = 0; v < 4; v++) \
    br[v] = *(const bf16x8*)&Bs[buf][raB + v * 512]; } while (0)
// SM==1 unswapped (store col=l16); else swapped (row=l16, regs = 4 cols)
#define MFALL() do { _Pragma("unroll") for (int u = 0; u < 8; u++) \
    _Pragma("unroll") for (int v = 0; v < 4; v++) { \
        if (SM == 1) acc[u][v] = __builtin_amdgcn_mfma_f32_16x16x32_bf16( \
            ar[u], br[v], acc[u][v], 0, 0, 0); \
        else acc[u][v] = __builtin_amdgcn_mfma_f32_16x16x32_bf16( \
            br[v], ar[u], acc[u][v], 0, 0, 0); \
    } } while (0)

    const int NT = K >> 5;   // K-tiles of 32

    for (int t = 0; t < NT; t++) {
        const int bcur = t & 1;
        // drain own stage(t) loads; barrier publishes ALL waves' DMA.
        // SB fences pin the barrier; inside the tile the compiler is free
        // to interleave ds_reads, staging and MFMA with counted waits.
        VMW(0);
        __builtin_amdgcn_sched_barrier(0);
        __builtin_amdgcn_s_barrier();
        __builtin_amdgcn_sched_barrier(0);
        LDA8(bcur); LDB4(bcur);
        if (t + 1 < NT) {
            const int kstg = (t + 1) << 5;
            STA(bcur ^ 1, 0, kstg); STA(bcur ^ 1, 1, kstg);
            STB(bcur ^ 1, 0, kstg); STB(bcur ^ 1, 1, kstg);
        }
        __builtin_amdgcn_s_setprio(1);
        MFALL();
        __builtin_amdgcn_s_setprio(0);
    }

    // ---- epilogue (last stage drained at top of t=NT-1) ----
    const long coff = h * Ch + (long)bi * Cb;
    if (SM == 0) {
        unsigned short* Cp = (unsigned short*)C + coff;
#pragma unroll
        for (int mi = 0; mi < 8; mi++) {
            const long rb = (long)(m0 + wm * 128 + mi * 16 + l16) * ldc;
#pragma unroll
            for (int ni = 0; ni < 4; ni++) {
                const int col = n0 + wn * 64 + ni * 16 + (quad << 2);
                us4 val = { f2bf(acc[mi][ni][0]), f2bf(acc[mi][ni][1]),
                            f2bf(acc[mi][ni][2]), f2bf(acc[mi][ni][3]) };
                *(us4*)&Cp[rb + col] = val;
            }
        }
    } else if (SM == 2) {
        float* Cp = (float*)C + coff;
#pragma unroll
        for (int mi = 0; mi < 8; mi++) {
            const long rb = (long)(m0 + wm * 128 + mi * 16 + l16) * ldc;
#pragma unroll
            for (int ni = 0; ni < 4; ni++) {
                const int col = n0 + wn * 64 + ni * 16 + (quad << 2);
                float4 v4 = { acc[mi][ni][0], acc[mi][ni][1],
                              acc[mi][ni][2], acc[mi][ni][3] };
                *(float4*)&Cp[rb + col] = v4;
            }
        }
    } else if (SM == 1) {  // VhT store, unswapped layout, us4 along s
        unsigned short* Cp = (unsigned short*)C;
#pragma unroll
        for (int mi = 0; mi < 8; mi++) {
#pragma unroll
            for (int ni = 0; ni < 4; ni++) {
                const int col = n0 + wn * 64 + ni * 16 + l16;
                const int h2 = col >> 9, d = col & 511;
                const int rowb = m0 + wm * 128 + mi * 16 + (quad << 2);
                const int bi2 = rowb >> 10, s = rowb & 1023;
                us4 val = { f2bf(acc[mi][ni][0]), f2bf(acc[mi][ni][1]),
                            f2bf(acc[mi][ni][2]), f2bf(acc[mi][ni][3]) };
                *(us4*)&Cp[(((long)(h2 * bg + bi2) * 512 + d) << 10) + s] = val;
            }
        }
    } else if (SM == 3) {
        // scores epilogue (swapped: row=l16, regs = 4 cols). Mask applied only
        // when the per-(row, 256-col-block) flag is set.
        unsigned short* Cp = (unsigned short*)C + coff;
        const unsigned char* mb = mask + ((long)(b0 + bi) << 20);
        const unsigned char* mfb = mflag + ((long)(b0 + bi) << 12);
        const int slot = (n0 >> 8) * 4 + wn;       // 4 n-blocks x 4 wn
        float* Lz = L + ((long)(slot * gridDim.z + z) << 10);
#pragma unroll
        for (int mi = 0; mi < 8; mi++) {
            const int row = m0 + wm * 128 + mi * 16 + l16;
            const long rb = (long)row * ldc;
            const unsigned char fl = mfb[(row << 2) + (n0 >> 8)];
            float rs = 0.f;
#pragma unroll
            for (int ni = 0; ni < 4; ni++) {
                const int col = n0 + wn * 64 + ni * 16 + (quad << 2);
                float p0 = __expf(acc[mi][ni][0] * inv_temp);
                float p1 = __expf(acc[mi][ni][1] * inv_temp);
                float p2 = __expf(acc[mi][ni][2] * inv_temp);
                float p3 = __expf(acc[mi][ni][3] * inv_temp);
                if (fl) {
                    const uchar4 mv = *(const uchar4*)&mb[((long)row << 10) + col];
                    if (mv.x) p0 = 0.f;
                    if (mv.y) p1 = 0.f;
                    if (mv.z) p2 = 0.f;
                    if (mv.w) p3 = 0.f;
                }
                us4 val = { f2bf(p0), f2bf(p1), f2bf(p2), f2bf(p3) };
                *(us4*)&Cp[rb + col] = val;
                rs += p0 + p1 + p2 + p3;
            }
            rs += __shfl_xor(rs, 16);
            rs += __shfl_xor(rs, 32);
            if (quad == 0) Lz[row] = rs;
        }
    } else {
        // PV epilogue: scale by 1/Ls (LDS), us4 along 4 consecutive cols.
        unsigned short* Cp = (unsigned short*)C + coff;
#pragma unroll
        for (int mi = 0; mi < 8; mi++) {
            const int ro = wm * 128 + mi * 16 + l16;
            const float inv = 1.0f / Ls[ro];
            const long rb = (long)(m0 + ro) * ldc;
#pragma unroll
            for (int ni = 0; ni < 4; ni++) {
                const int col = n0 + wn * 64 + ni * 16 + (quad << 2);
                us4 val = { f2bf(acc[mi][ni][0] * inv), f2bf(acc[mi][ni][1] * inv),
                            f2bf(acc[mi][ni][2] * inv), f2bf(acc[mi][ni][3] * inv) };
                *(us4*)&Cp[rb + col] = val;
            }
        }
    }
#undef STA
#undef STB
#undef LDA8
#undef LDB4
#undef MFALL
}
#undef VMW

// ---------------------------------------------------------------------------
// Fused: sum 8 split-K partials (f32, rows of 512) + LayerNorm -> f32 out.
// ---------------------------------------------------------------------------
__global__ __launch_bounds__(256) void ln_rows_red8(
    const float* __restrict__ Yp, long zs,
    const float* __restrict__ gamma,
    const float* __restrict__ beta,
    float* __restrict__ out)
{
    __shared__ float red[4];
    const long row = blockIdx.x;
    const float* y = Yp + (row << 9);
    const int tid = threadIdx.x;
    const int wave = tid >> 6, lane = tid & 63;

    float v0 = 0.f, v1 = 0.f;
#pragma unroll
    for (int s = 0; s < 8; s++) {
        v0 += y[s * zs + tid];
        v1 += y[s * zs + tid + 256];
    }
    float sm = v0 + v1;
#pragma unroll
    for (int i = 32; i > 0; i >>= 1) sm += __shfl_xor(sm, i);
    if (lane == 0) red[wave] = sm;
    __syncthreads();
    sm = red[0] + red[1] + red[2] + red[3];
    __syncthreads();
    const float mu = sm * (1.0f / 512.0f);

    const float d0 = v0 - mu, d1 = v1 - mu;
    float sq = d0 * d0 + d1 * d1;
#pragma unroll
    for (int i = 32; i > 0; i >>= 1) sq += __shfl_xor(sq, i);
    if (lane == 0) red[wave] = sq;
    __syncthreads();
    sq = red[0] + red[1] + red[2] + red[3];
    const float inv = rsqrtf(sq * (1.0f / 512.0f) + 1e-5f);

    out[(row << 9) + tid]       = d0 * inv * gamma[tid]       + beta[tid];
    out[(row << 9) + tid + 256] = d1 * inv * gamma[tid + 256] + beta[tid + 256];
}

// ---------------------------------------------------------------------------
extern "C" void kernel_launch(void* const* d_in, const int* in_sizes, int n_in,
                              void* d_out, int out_size, void* d_ws, size_t ws_size,
                              hipStream_t stream)
{
    const float* q_f  = (const float*)d_in[0];
    const float* k_f  = (const float*)d_in[1];
    const float* v_f  = (const float*)d_in[2];
    const float* Wq_f = (const float*)d_in[3];
    const float* Wk_f = (const float*)d_in[4];
    const float* Wv_f = (const float*)d_in[5];
    const float* Wo_f = (const float*)d_in[6];
    const float* ga_f = (const float*)d_in[7];
    const float* be_f = (const float*)d_in[8];
    const unsigned char* mask = (const unsigned char*)d_in[9];
    float* out = (float*)d_out;

    constexpr int B = 8, S = 1024, DM = 512, H = 8, DH = 512, HD = H * DH;  // HD=4096
    const float inv_temp = 0.044194173824159216f;  // 1/sqrt(512)

    size_t off = 0;
    auto alloc = [&](size_t bytes) {
        void* p = (char*)d_ws + off;
        off += (bytes + 255) & ~(size_t)255;
        return p;
    };
    unsigned short* qb  = (unsigned short*)alloc((size_t)B * S * DM * 2);
    unsigned short* kb  = (unsigned short*)alloc((size_t)B * S * DM * 2);
    unsigned short* vb  = (unsigned short*)alloc((size_t)B * S * DM * 2);
    unsigned short* WqT = (unsigned short*)alloc((size_t)HD * DM * 2);
    unsigned short* WkT = (unsigned short*)alloc((size_t)HD * DM * 2);
    unsigned short* WvT = (unsigned short*)alloc((size_t)HD * DM * 2);
    unsigned short* WoT = (unsigned short*)alloc((size_t)DH * HD * 2);
    unsigned char* mf   = (unsigned char*)alloc((size_t)B * S * 4);  // mask flags
    const size_t fixed = off;

    // AO aliases Qh (dead after scores); Ypart aliases P (dead after PV).
    const size_t perbatch = (size_t)3 * S * HD * 2   // Qh(/AO), Kh, VhT
                          + (size_t)H * S * S * 2    // P / Ypart (>= 8*S*DH*4)
                          + (size_t)16 * H * S * 4   // Lp (16 partial slots)
                          + 8 * 256;
    int bg = 8;
    while (bg > 1 && fixed + perbatch * (size_t)bg > ws_size) bg >>= 1;

    unsigned short* Qh  = (unsigned short*)alloc((size_t)bg * S * HD * 2);
    unsigned short* Kh  = (unsigned short*)alloc((size_t)bg * S * HD * 2);
    unsigned short* VhT = (unsigned short*)alloc((size_t)bg * S * HD * 2);
    unsigned short* AO  = Qh;  // alias: Qh dead once scores completes
    float* Lp = (float*)alloc((size_t)16 * H * bg * S * 4);
    void* PY = alloc((size_t)H * bg * S * S * 2);  // >= 8*bg*S*DH*4
    unsigned short* P = (unsigned short*)PY;
    float* Ypart = (float*)PY;

    // ---- canonicalization: f32 -> bf16 (+ weight transposes, mask flags) ----
    const long nqkv4 = (long)B * S * DM / 4;
    conv_f32_bf16<<<2048, 256, 0, stream>>>(q_f, qb, nqkv4);
    conv_f32_bf16<<<2048, 256, 0, stream>>>(k_f, kb, nqkv4);
    conv_f32_bf16<<<2048, 256, 0, stream>>>(v_f, vb, nqkv4);
    transpose_f32_bf16<<<dim3(HD / 64, DM / 64), 256, 0, stream>>>(Wq_f, WqT, DM, HD);
    transpose_f32_bf16<<<dim3(HD / 64, DM / 64), 256, 0, stream>>>(Wk_f, WkT, DM, HD);
    transpose_f32_bf16<<<dim3(HD / 64, DM / 64), 256, 0, stream>>>(Wv_f, WvT, DM, HD);
    transpose_f32_bf16<<<dim3(DH / 64, HD / 64), 256, 0, stream>>>(Wo_f, WoT, HD, DH);
    mask_any256<<<dim3(B * S), 256, 0, stream>>>(mask, mf);

    for (int g = 0; g < B / bg; g++) {
        const long inoff = (long)g * bg * S * DM;
        const int  Mg = bg * S;
        const int  Z  = H * bg;

        // ---- QKV projections: (Mg x 512) x (512 x 4096) ----
        gemm8w_bt<0, 1><<<dim3(HD / 256, Mg / 256, 1), 512, 0, stream>>>(
            qb + inoff, WqT, Qh, DM, DM, DM, HD, 0, 0, 0, 0, 0, 0, bg,
            nullptr, nullptr, nullptr, 0.f, 0);
        gemm8w_bt<0, 1><<<dim3(HD / 256, Mg / 256, 1), 512, 0, stream>>>(
            kb + inoff, WkT, Kh, DM, DM, DM, HD, 0, 0, 0, 0, 0, 0, bg,
            nullptr, nullptr, nullptr, 0.f, 0);
        gemm8w_bt<1, 1><<<dim3(HD / 256, Mg / 256, 1), 512, 0, stream>>>(
            vb + inoff, WvT, VhT, DM, DM, DM, HD, 0, 0, 0, 0, 0, 0, bg,
            nullptr, nullptr, nullptr, 0.f, 0);

        // ---- fused scores+exp+mask, z-chunked XCD swizzle ----
        gemm8w_bt<3, 2><<<dim3(S / 256, S / 256, Z), 512, 0, stream>>>(
            Qh, Kh, P, DH, HD, HD, S,
            (long)DH, (long)S * HD,
            (long)DH, (long)S * HD,
            (long)bg * S * S, (long)S * S,
            bg, mask, mf, Lp, inv_temp, g * bg);

        // ---- PV with 1/L normalization, z-chunked XCD swizzle ----
        gemm8w_bt<4, 2><<<dim3(DH / 256, S / 256, Z), 512, 0, stream>>>(
            P, VhT, AO, S, S, S, HD,
            (long)bg * S * S, (long)S * S,
            (long)bg * DH * S, (long)DH * S,
            (long)DH, (long)S * HD,
            bg, nullptr, nullptr, Lp, 0.f, 0);

        // ---- O-projection, split-K x8 -> Ypart (256 blocks, full CU cover) ----
        gemm8w_bt<2, 1><<<dim3(DH / 256, Mg / 256, 8), 512, 0, stream>>>(
            AO, WoT, Ypart, HD / 8, HD, HD, DH,
            512, 0, 512, 0, (long)Mg * DH, 0, 1,
            nullptr, nullptr, nullptr, 0.f, 0);

        // ---- reduce partials + LayerNorm -> f32 out ----
        ln_rows_red8<<<dim3(Mg), 256, 0, stream>>>(
            Ypart, (long)Mg * DH, ga_f, be_f, out + (long)g * bg * S * DH);
    }
}

// Round 8
// 571.563 us; speedup vs baseline: 1.0372x; 1.0372x over previous
//
#include <hip/hip_runtime.h>

typedef __attribute__((ext_vector_type(8))) short bf16x8;
typedef __attribute__((ext_vector_type(4))) float f32x4;
typedef __attribute__((ext_vector_type(4))) unsigned short us4;

typedef __attribute__((address_space(3))) void lds_void_t;
typedef const __attribute__((address_space(1))) void gbl_void_t;

__device__ __forceinline__ unsigned short f2bf(float f) {
    union { float f; unsigned int i; } x; x.f = f;
    unsigned int u = x.i;
    unsigned int r = (u + 0x7FFFu + ((u >> 16) & 1u)) >> 16;  // RNE
    return (unsigned short)r;
}

// ---------------------------------------------------------------------------
// f32 -> bf16 convert, 4 elems/thread, grid-stride.
// ---------------------------------------------------------------------------
__global__ __launch_bounds__(256) void conv_f32_bf16(
    const float* __restrict__ src, unsigned short* __restrict__ dst, long n4)
{
    long i = (long)blockIdx.x * blockDim.x + threadIdx.x;
    const long stride = (long)gridDim.x * blockDim.x;
    const float4* s = (const float4*)src;
    for (; i < n4; i += stride) {
        float4 v = s[i];
        us4 o = { f2bf(v.x), f2bf(v.y), f2bf(v.z), f2bf(v.w) };
        *(us4*)&dst[i * 4] = o;
    }
}

// ---------------------------------------------------------------------------
// Transpose: W(K x N) f32 -> Wt(N x K) bf16. 64x64 LDS tiles.
// ---------------------------------------------------------------------------
__global__ __launch_bounds__(256) void transpose_f32_bf16(
    const float* __restrict__ W, unsigned short* __restrict__ Wt, int K, int N)
{
    __shared__ unsigned short t[64][65];
    const int n0 = blockIdx.x * 64, k0 = blockIdx.y * 64;
    const int tid = threadIdx.x;
#pragma unroll
    for (int i = 0; i < 16; i++) {
        const int idx = tid + i * 256;
        const int r = idx >> 6, c = idx & 63;
        t[c][r] = f2bf(W[(long)(k0 + r) * N + (n0 + c)]);
    }
    __syncthreads();
#pragma unroll
    for (int i = 0; i < 16; i++) {
        const int idx = tid + i * 256;
        const int r = idx >> 6, c = idx & 63;
        Wt[(long)(n0 + r) * K + (k0 + c)] = t[r][c];
    }
}

// ---------------------------------------------------------------------------
// Mask summary: mf[b][row][nblk] = any(mask[b][row][nblk*256 .. +256)).
// ---------------------------------------------------------------------------
__global__ __launch_bounds__(256) void mask_any256(
    const unsigned char* __restrict__ mask, unsigned char* __restrict__ mf)
{
    const long row = blockIdx.x;                 // b*1024 + s
    const int tid = threadIdx.x;
    const unsigned int v = *(const unsigned int*)&mask[(row << 10) + (tid << 2)];
    const unsigned long long b = __ballot(v != 0u);
    if ((tid & 63) == 0) mf[(row << 2) + (tid >> 6)] = b ? 1 : 0;
}

// ---------------------------------------------------------------------------
// 256x256 bf16 GEMM, 8 waves (512 thr), wave tile 128x64, acc 8x4 f32x4.
// r8 change (single variable vs r7): BK=32 -> BK=64. Five schedule variants
// all pinned at ~600 TF / 23% MfmaUtil == the documented m233 2-phase wall.
// Per-tile wall measured 8.4k cyc vs 2.5k cyc of MFMA-pipe need -> ~6k cyc
// per-tile overhead. Hypothesis: overhead is per-tile-CONSTANT (barrier
// convoy), so doubling K per tile at fixed total work halves it.
// LDS: 2 buf x (A 256x64 + B 256x64) bf16 = 128 KiB (+1 KiB Ls) -> 1 blk/CU
// (r4-vs-r6: residency worth only ~3%). NT = K/64 (halved).
// Layout: each buffer is 2 k-halves, each k-half = the verified BK=32 layout
// ([256 rows][32 elems], 16-row x 32k per gload, linear dest). Same verified
// swizzle involution per half: stage source chunk (lane&3)^((lane>>3)&3),
// read chunk quad^((l16>>1)&3) (0 bank conflicts, r3-r7).
// Per tile t: VMW(0) [drains stage(t), issued 1 tile ago]; SB; s_barrier; SB;
//   {reads kh0 (12 b128) || stage tile t+1 (8 gloads)}; prio1; 32 MFMA; prio0;
//   reads kh1; prio1; 32 MFMA; prio0.   (frag regs reused across halves)
// Correctness: RAW: every wave VMW(0)+barrier before reads of tile t.
// WAR: buf^1's reads at t-1 are MFMA operands -> drained before that wave's
// last MFMA of t-1 -> before it reaches bar(t) -> before any stage(t+1).
// SM: 0 bf16 row-major (swapped mfma -> regs = 4 consecutive cols, us4)
//     1 VhT head-split-transpose (UNswapped, us4 along s)
//     2 f32 row-major (swapped, float4)
//     3 scores-fused: P=exp(s*it), mask via per-(row,nblk) flag; us4 stores;
//        row-sums -> Lp[(nb*4+wn)][z][row] (16 exclusive slots)
//     4 PV: scale by 1/sum_16(Lp), Ls[256] LDS table from prologue
// SWZ: 0 none | 1 within-plane XCD chunk | 2 whole-grid z-chunked XCD swizzle
// ---------------------------------------------------------------------------
#define VMW(n) asm volatile("s_waitcnt vmcnt(" #n ")" ::: "memory")

template <int SM, int SWZ>
__global__ __launch_bounds__(512, 2) void gemm8w_bt(
    const unsigned short* __restrict__ A,
    const unsigned short* __restrict__ Bt,
    void* __restrict__ C,
    int K, int lda, int ldb, int ldc,
    long Ah, long Ab, long Bh, long Bb, long Ch, long Cb,
    int bg,
    const unsigned char* __restrict__ mask,
    const unsigned char* __restrict__ mflag,
    float* __restrict__ L,
    float inv_temp, int b0)
{
    const int tid  = threadIdx.x;
    const int wave = tid >> 6;
    const int lane = tid & 63;
    const int quad = lane >> 4;
    const int l16  = lane & 15;
    const int wm   = wave >> 2;   // 0..1 : M-wave (rows wm*128..+127)
    const int wn   = wave & 3;    // 0..3 : N-wave (cols wn*64..+63)

    int z, m0, n0;
    if (SWZ == 2) {
        const int gx = gridDim.x, gxy = gx * gridDim.y;
        const int tot = gxy * gridDim.z;
        int Lb = (blockIdx.z * gridDim.y + blockIdx.y) * gx + blockIdx.x;
        int t = (Lb & 7) * (tot >> 3) + (Lb >> 3);
        z = t / gxy;
        const int rem = t - z * gxy;
        const int by = rem / gx;
        m0 = by << 8; n0 = (rem - by * gx) << 8;
    } else if (SWZ == 1) {
        z = blockIdx.z;
        int lin = blockIdx.y * gridDim.x + blockIdx.x;
        const int q8 = (gridDim.x * gridDim.y) >> 3;
        lin = (lin & 7) * q8 + (lin >> 3);
        const int by = lin / gridDim.x;
        m0 = by << 8; n0 = (lin - by * gridDim.x) << 8;
    } else {
        z = blockIdx.z; m0 = blockIdx.y << 8; n0 = blockIdx.x << 8;
    }

    const int h  = z / bg;
    const int bi = z - h * bg;
    A  += h * Ah + (long)bi * Ab;
    Bt += h * Bh + (long)bi * Bb;

    // [buf][k-half(2) x 256 rows x 32 elems] = 16384 shorts per buf
    __shared__ __align__(16) unsigned short As[2][16384];
    __shared__ __align__(16) unsigned short Bs[2][16384];
    __shared__ float Ls[256];  // PV: summed softmax denominators

    // ---- staging: linear LDS dest, inverse-swizzled global source ----
    const int srow = lane >> 2;
    const int scol = ((lane & 3) ^ ((lane >> 3) & 3)) << 3;
    const unsigned short* Ag = A + (long)(m0 + wave * 16 + srow) * lda + scol;
    const unsigned short* Bg = Bt + (long)(n0 + wave * 16 + srow) * ldb + scol;

// one gload: 16 rows (hh*128 + wave*16 +) x 32 k-elems of k-half kk
#define STA(buf, hh, kk, kt) __builtin_amdgcn_global_load_lds( \
        (gbl_void_t*)(Ag + (long)(hh) * 128 * lda + (kt) + (kk) * 32), \
        (lds_void_t*)&As[buf][(kk) * 8192 + ((hh) << 12) + (wave << 9)], 16, 0, 0)
#define STB(buf, hh, kk, kt) __builtin_amdgcn_global_load_lds( \
        (gbl_void_t*)(Bg + (long)(hh) * 128 * ldb + (kt) + (kk) * 32), \
        (lds_void_t*)&Bs[buf][(kk) * 8192 + ((hh) << 12) + (wave << 9)], 16, 0, 0)
#define STAGE(buf, kt) do { \
    STA(buf, 0, 0, kt); STA(buf, 0, 1, kt); STA(buf, 1, 0, kt); STA(buf, 1, 1, kt); \
    STB(buf, 0, 0, kt); STB(buf, 0, 1, kt); STB(buf, 1, 0, kt); STB(buf, 1, 1, kt); \
    } while (0)

    // prologue: stage tile 0 (8 gloads)
    STAGE(0, 0);

    if (SM == 4) {
        if (tid < 256) {
            const float* Lz = L + ((long)z << 10) + m0 + tid;
            const long sls = (long)gridDim.z << 10;
            float s = 0.f;
#pragma unroll
            for (int sl = 0; sl < 16; sl++) s += Lz[sl * sls];
            Ls[tid] = s;
        }
    }

    // ---- fragment reads (swizzled addr, verified pair with staging) ----
    const int kof = (quad ^ ((l16 >> 1) & 3)) << 3;
    const int raA = ((wm * 128 + l16) << 5) + kof;
    const int raB = ((wn * 64 + l16) << 5) + kof;

    bf16x8 ar[8];
    bf16x8 br[4];
    f32x4 acc[8][4];
#pragma unroll
    for (int i2 = 0; i2 < 8; i2++)
#pragma unroll
        for (int j2 = 0; j2 < 4; j2++) acc[i2][j2] = (f32x4){0.f, 0.f, 0.f, 0.f};

#define LDA8(buf, kh) do { _Pragma("unroll") for (int u = 0; u < 8; u++) \
    ar[u] = *(const bf16x8*)&As[buf][(kh) * 8192 + raA + u * 512]; } while (0)
#define LDB4(buf, kh) do { _Pragma("unroll") for (int v = 0; v < 4; v++) \
    br[v] = *(const bf16x8*)&Bs[buf][(kh) * 8192 + raB + v * 512]; } while (0)
// SM==1 unswapped (store col=l16); else swapped (row=l16, regs = 4 cols)
#define MFALL() do { _Pragma("unroll") for (int u = 0; u < 8; u++) \
    _Pragma("unroll") for (int v = 0; v < 4; v++) { \
        if (SM == 1) acc[u][v] = __builtin_amdgcn_mfma_f32_16x16x32_bf16( \
            ar[u], br[v], acc[u][v], 0, 0, 0); \
        else acc[u][v] = __builtin_amdgcn_mfma_f32_16x16x32_bf16( \
            br[v], ar[u], acc[u][v], 0, 0, 0); \
    } } while (0)

    const int NT = K >> 6;   // K-tiles of 64

    for (int t = 0; t < NT; t++) {
        const int bcur = t & 1;
        // drain own stage(t) loads; barrier publishes ALL waves' DMA.
        VMW(0);
        __builtin_amdgcn_sched_barrier(0);
        __builtin_amdgcn_s_barrier();
        __builtin_amdgcn_sched_barrier(0);
        // k-half 0 reads + next-tile staging, then MFMA cluster
        LDA8(bcur, 0); LDB4(bcur, 0);
        if (t + 1 < NT) STAGE(bcur ^ 1, (t + 1) << 6);
        __builtin_amdgcn_s_setprio(1);
        MFALL();
        __builtin_amdgcn_s_setprio(0);
        // k-half 1 reads, then MFMA cluster (frag regs reused)
        LDA8(bcur, 1); LDB4(bcur, 1);
        __builtin_amdgcn_s_setprio(1);
        MFALL();
        __builtin_amdgcn_s_setprio(0);
    }

    // ---- epilogue (last stage drained at top of t=NT-1) ----
    const long coff = h * Ch + (long)bi * Cb;
    if (SM == 0) {
        unsigned short* Cp = (unsigned short*)C + coff;
#pragma unroll
        for (int mi = 0; mi < 8; mi++) {
            const long rb = (long)(m0 + wm * 128 + mi * 16 + l16) * ldc;
#pragma unroll
            for (int ni = 0; ni < 4; ni++) {
                const int col = n0 + wn * 64 + ni * 16 + (quad << 2);
                us4 val = { f2bf(acc[mi][ni][0]), f2bf(acc[mi][ni][1]),
                            f2bf(acc[mi][ni][2]), f2bf(acc[mi][ni][3]) };
                *(us4*)&Cp[rb + col] = val;
            }
        }
    } else if (SM == 2) {
        float* Cp = (float*)C + coff;
#pragma unroll
        for (int mi = 0; mi < 8; mi++) {
            const long rb = (long)(m0 + wm * 128 + mi * 16 + l16) * ldc;
#pragma unroll
            for (int ni = 0; ni < 4; ni++) {
                const int col = n0 + wn * 64 + ni * 16 + (quad << 2);
                float4 v4 = { acc[mi][ni][0], acc[mi][ni][1],
                              acc[mi][ni][2], acc[mi][ni][3] };
                *(float4*)&Cp[rb + col] = v4;
            }
        }
    } else if (SM == 1) {  // VhT store, unswapped layout, us4 along s
        unsigned short* Cp = (unsigned short*)C;
#pragma unroll
        for (int mi = 0; mi < 8; mi++) {
#pragma unroll
            for (int ni = 0; ni < 4; ni++) {
                const int col = n0 + wn * 64 + ni * 16 + l16;
                const int h2 = col >> 9, d = col & 511;
                const int rowb = m0 + wm * 128 + mi * 16 + (quad << 2);
                const int bi2 = rowb >> 10, s = rowb & 1023;
                us4 val = { f2bf(acc[mi][ni][0]), f2bf(acc[mi][ni][1]),
                            f2bf(acc[mi][ni][2]), f2bf(acc[mi][ni][3]) };
                *(us4*)&Cp[(((long)(h2 * bg + bi2) * 512 + d) << 10) + s] = val;
            }
        }
    } else if (SM == 3) {
        // scores epilogue (swapped: row=l16, regs = 4 cols). Mask applied only
        // when the per-(row, 256-col-block) flag is set.
        unsigned short* Cp = (unsigned short*)C + coff;
        const unsigned char* mb = mask + ((long)(b0 + bi) << 20);
        const unsigned char* mfb = mflag + ((long)(b0 + bi) << 12);
        const int slot = (n0 >> 8) * 4 + wn;       // 4 n-blocks x 4 wn
        float* Lz = L + ((long)(slot * gridDim.z + z) << 10);
#pragma unroll
        for (int mi = 0; mi < 8; mi++) {
            const int row = m0 + wm * 128 + mi * 16 + l16;
            const long rb = (long)row * ldc;
            const unsigned char fl = mfb[(row << 2) + (n0 >> 8)];
            float rs = 0.f;
#pragma unroll
            for (int ni = 0; ni < 4; ni++) {
                const int col = n0 + wn * 64 + ni * 16 + (quad << 2);
                float p0 = __expf(acc[mi][ni][0] * inv_temp);
                float p1 = __expf(acc[mi][ni][1] * inv_temp);
                float p2 = __expf(acc[mi][ni][2] * inv_temp);
                float p3 = __expf(acc[mi][ni][3] * inv_temp);
                if (fl) {
                    const uchar4 mv = *(const uchar4*)&mb[((long)row << 10) + col];
                    if (mv.x) p0 = 0.f;
                    if (mv.y) p1 = 0.f;
                    if (mv.z) p2 = 0.f;
                    if (mv.w) p3 = 0.f;
                }
                us4 val = { f2bf(p0), f2bf(p1), f2bf(p2), f2bf(p3) };
                *(us4*)&Cp[rb + col] = val;
                rs += p0 + p1 + p2 + p3;
            }
            rs += __shfl_xor(rs, 16);
            rs += __shfl_xor(rs, 32);
            if (quad == 0) Lz[row] = rs;
        }
    } else {
        // PV epilogue: scale by 1/Ls (LDS), us4 along 4 consecutive cols.
        unsigned short* Cp = (unsigned short*)C + coff;
#pragma unroll
        for (int mi = 0; mi < 8; mi++) {
            const int ro = wm * 128 + mi * 16 + l16;
            const float inv = 1.0f / Ls[ro];
            const long rb = (long)(m0 + ro) * ldc;
#pragma unroll
            for (int ni = 0; ni < 4; ni++) {
                const int col = n0 + wn * 64 + ni * 16 + (quad << 2);
                us4 val = { f2bf(acc[mi][ni][0] * inv), f2bf(acc[mi][ni][1] * inv),
                            f2bf(acc[mi][ni][2] * inv), f2bf(acc[mi][ni][3] * inv) };
                *(us4*)&Cp[rb + col] = val;
            }
        }
    }
#undef STA
#undef STB
#undef STAGE
#undef LDA8
#undef LDB4
#undef MFALL
}
#undef VMW

// ---------------------------------------------------------------------------
// Fused: sum 8 split-K partials (f32, rows of 512) + LayerNorm -> f32 out.
// ---------------------------------------------------------------------------
__global__ __launch_bounds__(256) void ln_rows_red8(
    const float* __restrict__ Yp, long zs,
    const float* __restrict__ gamma,
    const float* __restrict__ beta,
    float* __restrict__ out)
{
    __shared__ float red[4];
    const long row = blockIdx.x;
    const float* y = Yp + (row << 9);
    const int tid = threadIdx.x;
    const int wave = tid >> 6, lane = tid & 63;

    float v0 = 0.f, v1 = 0.f;
#pragma unroll
    for (int s = 0; s < 8; s++) {
        v0 += y[s * zs + tid];
        v1 += y[s * zs + tid + 256];
    }
    float sm = v0 + v1;
#pragma unroll
    for (int i = 32; i > 0; i >>= 1) sm += __shfl_xor(sm, i);
    if (lane == 0) red[wave] = sm;
    __syncthreads();
    sm = red[0] + red[1] + red[2] + red[3];
    __syncthreads();
    const float mu = sm * (1.0f / 512.0f);

    const float d0 = v0 - mu, d1 = v1 - mu;
    float sq = d0 * d0 + d1 * d1;
#pragma unroll
    for (int i = 32; i > 0; i >>= 1) sq += __shfl_xor(sq, i);
    if (lane == 0) red[wave] = sq;
    __syncthreads();
    sq = red[0] + red[1] + red[2] + red[3];
    const float inv = rsqrtf(sq * (1.0f / 512.0f) + 1e-5f);

    out[(row << 9) + tid]       = d0 * inv * gamma[tid]       + beta[tid];
    out[(row << 9) + tid + 256] = d1 * inv * gamma[tid + 256] + beta[tid + 256];
}

// ---------------------------------------------------------------------------
extern "C" void kernel_launch(void* const* d_in, const int* in_sizes, int n_in,
                              void* d_out, int out_size, void* d_ws, size_t ws_size,
                              hipStream_t stream)
{
    const float* q_f  = (const float*)d_in[0];
    const float* k_f  = (const float*)d_in[1];
    const float* v_f  = (const float*)d_in[2];
    const float* Wq_f = (const float*)d_in[3];
    const float* Wk_f = (const float*)d_in[4];
    const float* Wv_f = (const float*)d_in[5];
    const float* Wo_f = (const float*)d_in[6];
    const float* ga_f = (const float*)d_in[7];
    const float* be_f = (const float*)d_in[8];
    const unsigned char* mask = (const unsigned char*)d_in[9];
    float* out = (float*)d_out;

    constexpr int B = 8, S = 1024, DM = 512, H = 8, DH = 512, HD = H * DH;  // HD=4096
    const float inv_temp = 0.044194173824159216f;  // 1/sqrt(512)

    size_t off = 0;
    auto alloc = [&](size_t bytes) {
        void* p = (char*)d_ws + off;
        off += (bytes + 255) & ~(size_t)255;
        return p;
    };
    unsigned short* qb  = (unsigned short*)alloc((size_t)B * S * DM * 2);
    unsigned short* kb  = (unsigned short*)alloc((size_t)B * S * DM * 2);
    unsigned short* vb  = (unsigned short*)alloc((size_t)B * S * DM * 2);
    unsigned short* WqT = (unsigned short*)alloc((size_t)HD * DM * 2);
    unsigned short* WkT = (unsigned short*)alloc((size_t)HD * DM * 2);
    unsigned short* WvT = (unsigned short*)alloc((size_t)HD * DM * 2);
    unsigned short* WoT = (unsigned short*)alloc((size_t)DH * HD * 2);
    unsigned char* mf   = (unsigned char*)alloc((size_t)B * S * 4);  // mask flags
    const size_t fixed = off;

    // AO aliases Qh (dead after scores); Ypart aliases P (dead after PV).
    const size_t perbatch = (size_t)3 * S * HD * 2   // Qh(/AO), Kh, VhT
                          + (size_t)H * S * S * 2    // P / Ypart (>= 8*S*DH*4)
                          + (size_t)16 * H * S * 4   // Lp (16 partial slots)
                          + 8 * 256;
    int bg = 8;
    while (bg > 1 && fixed + perbatch * (size_t)bg > ws_size) bg >>= 1;

    unsigned short* Qh  = (unsigned short*)alloc((size_t)bg * S * HD * 2);
    unsigned short* Kh  = (unsigned short*)alloc((size_t)bg * S * HD * 2);
    unsigned short* VhT = (unsigned short*)alloc((size_t)bg * S * HD * 2);
    unsigned short* AO  = Qh;  // alias: Qh dead once scores completes
    float* Lp = (float*)alloc((size_t)16 * H * bg * S * 4);
    void* PY = alloc((size_t)H * bg * S * S * 2);  // >= 8*bg*S*DH*4
    unsigned short* P = (unsigned short*)PY;
    float* Ypart = (float*)PY;

    // ---- canonicalization: f32 -> bf16 (+ weight transposes, mask flags) ----
    const long nqkv4 = (long)B * S * DM / 4;
    conv_f32_bf16<<<2048, 256, 0, stream>>>(q_f, qb, nqkv4);
    conv_f32_bf16<<<2048, 256, 0, stream>>>(k_f, kb, nqkv4);
    conv_f32_bf16<<<2048, 256, 0, stream>>>(v_f, vb, nqkv4);
    transpose_f32_bf16<<<dim3(HD / 64, DM / 64), 256, 0, stream>>>(Wq_f, WqT, DM, HD);
    transpose_f32_bf16<<<dim3(HD / 64, DM / 64), 256, 0, stream>>>(Wk_f, WkT, DM, HD);
    transpose_f32_bf16<<<dim3(HD / 64, DM / 64), 256, 0, stream>>>(Wv_f, WvT, DM, HD);
    transpose_f32_bf16<<<dim3(DH / 64, HD / 64), 256, 0, stream>>>(Wo_f, WoT, HD, DH);
    mask_any256<<<dim3(B * S), 256, 0, stream>>>(mask, mf);

    for (int g = 0; g < B / bg; g++) {
        const long inoff = (long)g * bg * S * DM;
        const int  Mg = bg * S;
        const int  Z  = H * bg;

        // ---- QKV projections: (Mg x 512) x (512 x 4096) ----
        gemm8w_bt<0, 1><<<dim3(HD / 256, Mg / 256, 1), 512, 0, stream>>>(
            qb + inoff, WqT, Qh, DM, DM, DM, HD, 0, 0, 0, 0, 0, 0, bg,
            nullptr, nullptr, nullptr, 0.f, 0);
        gemm8w_bt<0, 1><<<dim3(HD / 256, Mg / 256, 1), 512, 0, stream>>>(
            kb + inoff, WkT, Kh, DM, DM, DM, HD, 0, 0, 0, 0, 0, 0, bg,
            nullptr, nullptr, nullptr, 0.f, 0);
        gemm8w_bt<1, 1><<<dim3(HD / 256, Mg / 256, 1), 512, 0, stream>>>(
            vb + inoff, WvT, VhT, DM, DM, DM, HD, 0, 0, 0, 0, 0, 0, bg,
            nullptr, nullptr, nullptr, 0.f, 0);

        // ---- fused scores+exp+mask, z-chunked XCD swizzle ----
        gemm8w_bt<3, 2><<<dim3(S / 256, S / 256, Z), 512, 0, stream>>>(
            Qh, Kh, P, DH, HD, HD, S,
            (long)DH, (long)S * HD,
            (long)DH, (long)S * HD,
            (long)bg * S * S, (long)S * S,
            bg, mask, mf, Lp, inv_temp, g * bg);

        // ---- PV with 1/L normalization, z-chunked XCD swizzle ----
        gemm8w_bt<4, 2><<<dim3(DH / 256, S / 256, Z), 512, 0, stream>>>(
            P, VhT, AO, S, S, S, HD,
            (long)bg * S * S, (long)S * S,
            (long)bg * DH * S, (long)DH * S,
            (long)DH, (long)S * HD,
            bg, nullptr, nullptr, Lp, 0.f, 0);

        // ---- O-projection, split-K x8 -> Ypart (256 blocks, full CU cover) ----
        gemm8w_bt<2, 1><<<dim3(DH / 256, Mg / 256, 8), 512, 0, stream>>>(
            AO, WoT, Ypart, HD / 8, HD, HD, DH,
            512, 0, 512, 0, (long)Mg * DH, 0, 1,
            nullptr, nullptr, nullptr, 0.f, 0);

        // ---- reduce partials + LayerNorm -> f32 out ----
        ln_rows_red8<<<dim3(Mg), 256, 0, stream>>>(
            Ypart, (long)Mg * DH, ga_f, be_f, out + (long)g * bg * S * DH);
    }
}